// Round 4
// baseline (296.646 us; speedup 1.0000x reference)
//
#include <hip/hip_runtime.h>
#include <hip/hip_bf16.h>

// Problem constants
#define DIMK   512
#define HEADS  8
#define DHEAD  64
#define SEQ    2048
#define BATCH  8
#define MROWS  (BATCH*SEQ)      // 16384
#define SCALE_LOG2E (0.044194173824159216f * 1.44269504088896340736f) // 512^-0.5 * log2(e)

typedef float fx4    __attribute__((ext_vector_type(4)));
typedef float f32x16 __attribute__((ext_vector_type(16)));
typedef short bf16x8 __attribute__((ext_vector_type(8)));
typedef short bf16x4 __attribute__((ext_vector_type(4)));

__device__ __forceinline__ short f2bf(float f) {
    union { float f; unsigned u; } x; x.f = f;
    unsigned r = (x.u + 0x7FFFu + ((x.u >> 16) & 1u)) >> 16;   // RNE
    return (short)r;
}

// pack two floats to two bf16 (round-half-up) in one dword via v_perm_b32
__device__ __forceinline__ unsigned pk2bf(float a, float b) {
    union { float f; unsigned u; } A, B; A.f = a; B.f = b;
    return __builtin_amdgcn_perm(B.u + 0x8000u, A.u + 0x8000u, 0x07060302u);
}

// single-instruction pack: dword = {bf16(a) lo, bf16(b) hi}, RNE
__device__ __forceinline__ unsigned cvtpk(float a, float b) {
    unsigned r;
    asm("v_cvt_pk_bf16_f32 %0, %1, %2" : "=v"(r) : "v"(a), "v"(b));
    return r;
}

__device__ __forceinline__ bf16x8 mk8(unsigned a, unsigned b, unsigned c, unsigned d) {
    union { unsigned u[4]; bf16x8 v; } x;
    x.u[0] = a; x.u[1] = b; x.u[2] = c; x.u[3] = d; return x.v;
}

// async global->LDS, 16B per lane; LDS dest = wave-uniform base + lane*16
__device__ __forceinline__ void ld16(const short* g, short* l) {
    __builtin_amdgcn_global_load_lds(
        (const __attribute__((address_space(1))) unsigned int*)g,
        (__attribute__((address_space(3))) unsigned int*)l, 16, 0, 0);
}

#define MFMA(a, b, c)   __builtin_amdgcn_mfma_f32_16x16x32_bf16(a, b, c, 0, 0, 0)
#define MFMA32(a, b, c) __builtin_amdgcn_mfma_f32_32x32x16_bf16(a, b, c, 0, 0, 0)

// ---------------------------------------------------------------- convert (x and m fused)
__global__ __launch_bounds__(256) void cvt_kernel(const float* __restrict__ x,
                                                  const float* __restrict__ m,
                                                  short* __restrict__ xb,
                                                  short* __restrict__ mb) {
    int bid = blockIdx.x;
    const float* src = (bid < 8192) ? x : m;
    short* dst = (bid < 8192) ? xb : mb;
    int i = (bid & 8191) * 256 + threadIdx.x;
    float4 v = ((const float4*)src)[i];
    bf16x4 o; o.x = f2bf(v.x); o.y = f2bf(v.y); o.z = f2bf(v.z); o.w = f2bf(v.w);
    ((bf16x4*)dst)[i] = o;
}

// ------------------------------------------------- weight transpose W[k][n] -> WT[n][k] bf16
__global__ __launch_bounds__(256) void wtrans_kernel(const float* __restrict__ Wq,
                                                     const float* __restrict__ Wk,
                                                     const float* __restrict__ Wv,
                                                     const float* __restrict__ Wo,
                                                     short* __restrict__ wT) {
    __shared__ float tile[32][33];
    const float* W = (blockIdx.z == 0) ? Wq : (blockIdx.z == 1) ? Wk
                   : (blockIdx.z == 2) ? Wv : Wo;
    short* dst = wT + (size_t)blockIdx.z * DIMK * DIMK;
    int n0 = blockIdx.x * 32, k0 = blockIdx.y * 32;
    int tx = threadIdx.x, ty = threadIdx.y;          // (32,8)
#pragma unroll
    for (int i = 0; i < 32; i += 8)
        tile[ty + i][tx] = W[(size_t)(k0 + ty + i) * DIMK + n0 + tx];
    __syncthreads();
#pragma unroll
    for (int i = 0; i < 32; i += 8)
        dst[(size_t)(n0 + ty + i) * DIMK + k0 + tx] = f2bf(tile[tx][ty + i]);
}

// ---------------------------------------------------------------- GEMM mainloop (m97-style)
// Stages A(128x512 act rows) and B(128x512 weight rows), BK=32, 16KB LDS, 2-barrier loop.
// OWN_B=1: acc[mi][nj] = D[weight][act] (lane: 4 consecutive weight rows = inner cols)
template<int OWN_B>
__device__ __forceinline__ void gemm97(const short* __restrict__ A,
                                       const short* __restrict__ B,
                                       short* lds, fx4 acc[2][8],
                                       int w, int lane, int q, int l15) {
    short* sA = lds;
    short* sB = lds + 4096;
    for (int k0 = 0; k0 < DIMK; k0 += 32) {
        __syncthreads();                         // prior iter's fragment reads complete
#pragma unroll
        for (int j = 0; j < 2; j++) {
            int c = w * 2 + j;
            ld16(A + (size_t)(c * 16 + l15) * DIMK + k0 + q * 8, sA + c * 512 + lane * 8);
            ld16(B + (size_t)(c * 16 + l15) * DIMK + k0 + q * 8, sB + c * 512 + lane * 8);
        }
        __syncthreads();                         // tile resident
        short* sOwn = OWN_B ? sB : sA;
        short* sAll = OWN_B ? sA : sB;
        bf16x8 o0 = *(bf16x8*)&sOwn[(w * 2 + 0) * 512 + lane * 8];
        bf16x8 o1 = *(bf16x8*)&sOwn[(w * 2 + 1) * 512 + lane * 8];
#pragma unroll
        for (int nt = 0; nt < 8; nt++) {
            bf16x8 f = *(bf16x8*)&sAll[nt * 512 + lane * 8];
            acc[0][nt] = MFMA(o0, f, acc[0][nt]);
            acc[1][nt] = MFMA(o1, f, acc[1][nt]);
        }
    }
}

// ---------------------------------------------------------------- Q projection
// grid (4, 128): x = inner tile, y = n tile. Q prescaled by SCALE*log2e.
__global__ __launch_bounds__(256) void proj_q(const short* __restrict__ xb,
                                              const short* __restrict__ wT,
                                              short* __restrict__ qkv) {
    __shared__ __attribute__((aligned(16))) short lds[8192];
    int t = threadIdx.x, lane = t & 63, q = lane >> 4, l15 = lane & 15;
    int w = __builtin_amdgcn_readfirstlane(t >> 6);
    const short* A = xb + (size_t)blockIdx.y * 128 * DIMK;
    const short* B = wT + (size_t)blockIdx.x * 128 * DIMK;
    fx4 acc[2][8] = {};
    gemm97<1>(A, B, lds, acc, w, lane, q, l15);
    const float sc = (float)SCALE_LOG2E;
#pragma unroll
    for (int mi = 0; mi < 2; mi++) {
        int inner0 = blockIdx.x * 128 + w * 32 + mi * 16 + q * 4;
        int h = inner0 >> 6, d0 = inner0 & 63;
#pragma unroll
        for (int nj = 0; nj < 8; nj++) {
            int gn = blockIdx.y * 128 + nj * 16 + l15;
            int b = gn >> 11, n = gn & 2047;
            uint2 pv;
            pv.x = pk2bf(acc[mi][nj][0] * sc, acc[mi][nj][1] * sc);
            pv.y = pk2bf(acc[mi][nj][2] * sc, acc[mi][nj][3] * sc);
            *(uint2*)&qkv[(((size_t)(b * 8 + h) * SEQ + n) << 6) + d0] = pv;
        }
    }
}

// ---------------------------------------------------------------- fused K+V projection
// grid (4, 128): both GEMMs share one staged mb A-tile per K-step: 3 LDS panels (A, Bk, Bv),
// 32 MFMA per K-step (vs 2x16 with separate blocks), 6 ld16/wave/step (vs 8), half the barriers.
__global__ __launch_bounds__(256) void proj_kv(const short* __restrict__ mb,
                                               const short* __restrict__ wT,
                                               short* __restrict__ qkv) {
    __shared__ __attribute__((aligned(16))) short lds[12288];   // 24 KB: sA | sBk | sBv
    int t = threadIdx.x, lane = t & 63, q = lane >> 4, l15 = lane & 15;
    int w = __builtin_amdgcn_readfirstlane(t >> 6);
    const short* A  = mb + (size_t)blockIdx.y * 128 * DIMK;
    const short* Bk = wT + (size_t)DIMK * DIMK + (size_t)blockIdx.x * 128 * DIMK;
    const short* Bv = wT + 2 * (size_t)DIMK * DIMK + (size_t)blockIdx.x * 128 * DIMK;
    short* sA  = lds;
    short* sBk = lds + 4096;
    short* sBv = lds + 8192;
    fx4 kacc[2][8] = {};   // OWN_B=1 layout: D[weight][act]
    fx4 vacc[2][8] = {};   // OWN_B=0 layout: D[act][weight]

    for (int k0 = 0; k0 < DIMK; k0 += 32) {
        __syncthreads();
#pragma unroll
        for (int j = 0; j < 2; j++) {
            int c = w * 2 + j;
            size_t ro = (size_t)(c * 16 + l15) * DIMK + k0 + q * 8;
            ld16(A + ro,  sA  + c * 512 + lane * 8);
            ld16(Bk + ro, sBk + c * 512 + lane * 8);
            ld16(Bv + ro, sBv + c * 512 + lane * 8);
        }
        __syncthreads();
        bf16x8 ok0 = *(bf16x8*)&sBk[(w * 2 + 0) * 512 + lane * 8];
        bf16x8 ok1 = *(bf16x8*)&sBk[(w * 2 + 1) * 512 + lane * 8];
        bf16x8 oa0 = *(bf16x8*)&sA [(w * 2 + 0) * 512 + lane * 8];
        bf16x8 oa1 = *(bf16x8*)&sA [(w * 2 + 1) * 512 + lane * 8];
#pragma unroll
        for (int nt = 0; nt < 8; nt++) {
            bf16x8 fa = *(bf16x8*)&sA[nt * 512 + lane * 8];
            kacc[0][nt] = MFMA(ok0, fa, kacc[0][nt]);
            kacc[1][nt] = MFMA(ok1, fa, kacc[1][nt]);
            bf16x8 fv = *(bf16x8*)&sBv[nt * 512 + lane * 8];
            vacc[0][nt] = MFMA(oa0, fv, vacc[0][nt]);
            vacc[1][nt] = MFMA(oa1, fv, vacc[1][nt]);
        }
    }

    // ---- K epilogue (verbatim mode-1): lane holds 4 consecutive inner (d) -> [bh][n][d]
    short* kdst = qkv + (size_t)MROWS * DIMK;
#pragma unroll
    for (int mi = 0; mi < 2; mi++) {
        int inner0 = blockIdx.x * 128 + w * 32 + mi * 16 + q * 4;
        int h = inner0 >> 6, d0 = inner0 & 63;
#pragma unroll
        for (int nj = 0; nj < 8; nj++) {
            int gn = blockIdx.y * 128 + nj * 16 + l15;
            int b = gn >> 11, n = gn & 2047;
            uint2 pv;
            pv.x = pk2bf(kacc[mi][nj][0], kacc[mi][nj][1]);
            pv.y = pk2bf(kacc[mi][nj][2], kacc[mi][nj][3]);
            *(uint2*)&kdst[(((size_t)(b * 8 + h) * SEQ + n) << 6) + d0] = pv;
        }
    }
    // ---- V epilogue (verbatim mode-2): lane holds 4 consecutive n (j) -> vT[bh*64+d][jperm]
    short* vdst = qkv + 2 * (size_t)MROWS * DIMK;
#pragma unroll
    for (int mt = 0; mt < 2; mt++) {
        int gm0 = blockIdx.y * 128 + w * 32 + mt * 16 + q * 4;  // global act row base
        int b = gm0 >> 11, j0 = gm0 & 2047;
        // stored offset = true j with bits 2<->3 swapped (quad-aligned, self-inverse) so attn's
        // exchange-free P fragments pair with matching V elements.
        int jp = (j0 & ~12) | ((j0 & 8) >> 1) | ((j0 & 4) << 1);
#pragma unroll
        for (int nt = 0; nt < 8; nt++) {
            int inner = blockIdx.x * 128 + nt * 16 + l15;       // h*64+d
            uint2 pv;
            pv.x = pk2bf(vacc[mt][nt][0], vacc[mt][nt][1]);
            pv.y = pk2bf(vacc[mt][nt][2], vacc[mt][nt][3]);
            *(uint2*)&vdst[((size_t)b * 512 + inner) * SEQ + jp] = pv;
        }
    }
}

// ---------------------------------------------------------------- output projection (transposed)
// grid (4, 128): x = out-col tile, y = m tile. Lane holds 4 consecutive out-cols -> float4 stores.
__global__ __launch_bounds__(256) void out_proj(const short* __restrict__ ob,
                                                const short* __restrict__ woT,
                                                const float* __restrict__ bo,
                                                float* __restrict__ out) {
    __shared__ __attribute__((aligned(16))) short lds[8192];
    int t = threadIdx.x, lane = t & 63, q = lane >> 4, l15 = lane & 15;
    int w = __builtin_amdgcn_readfirstlane(t >> 6);
    const short* A = ob + (size_t)blockIdx.y * 128 * DIMK;
    const short* B = woT + (size_t)blockIdx.x * 128 * DIMK;
    fx4 acc[2][8] = {};
    gemm97<1>(A, B, lds, acc, w, lane, q, l15);

#pragma unroll
    for (int mi = 0; mi < 2; mi++) {
        int gn0 = blockIdx.x * 128 + w * 32 + mi * 16 + q * 4;  // out col base
        float4 b4 = *(const float4*)&bo[gn0];
#pragma unroll
        for (int nj = 0; nj < 8; nj++) {
            int n = blockIdx.y * 128 + nj * 16 + l15;           // act row
            float4 v;
            v.x = acc[mi][nj][0] + b4.x;
            v.y = acc[mi][nj][1] + b4.y;
            v.z = acc[mi][nj][2] + b4.z;
            v.w = acc[mi][nj][3] + b4.w;
            *(float4*)&out[(size_t)n * DIMK + gn0] = v;
        }
    }
}

// ---------------------------------------------------------------- flash attention (S^T form, 32x32 MFMA)
// grid (64, 16). Wave w owns 32 q rows. KVBLK=64, double-buffered K/V in LDS, 16B-granule XOR
// swizzle (pre-swizzled global source, linear LDS dest, matching swizzled ds_read).
// Softmax fully in-register and exchange-free (see round-3 notes); V pre-permuted at store.
// This round: PV MFMAs for P[0..1] are issued BETWEEN the two exp/pack VALU bursts, and the
// row-sum adds moved after PV issue, to shrink the wave's serial VALU-only window.
__global__ __launch_bounds__(256, 4) void attn_kernel(const short* __restrict__ qg,
                                                      const short* __restrict__ kg,
                                                      const short* __restrict__ vg,
                                                      short* __restrict__ o) {
    // [buf0: K 4096 | V 4096][buf1: K | V] shorts = 32 KB
    __shared__ __attribute__((aligned(16))) short lds[16384];
    int t = threadIdx.x, lane = t & 63;
    int il = lane & 31, h = lane >> 5, il7 = il & 7;
    int w = __builtin_amdgcn_readfirstlane(t >> 6);
    int bh = blockIdx.x;
    int i0 = blockIdx.y * 128;
    const short* qbh = qg + (size_t)bh * SEQ * DHEAD;

    // staging lane constants: row-sub = lane>>3 (8 rows/instr), swizzled col granule
    int lr = lane >> 3;
    int lc = (lane & 7) ^ lr;                        // source col granule for this lane
    const short* kbase = kg + (size_t)bh * SEQ * DHEAD + (size_t)(w * 16 + lr) * DHEAD + lc * 8;
    const short* vbase = vg + (size_t)bh * DHEAD * SEQ + (size_t)(w * 16 + lr) * SEQ + lc * 8;

    auto issueKV = [&](int j0, short* bb) {
        const short* kj = kbase + (size_t)j0 * DHEAD;     // K rows j0 + w*16 + {0,8} + lr
        const short* vj = vbase + j0;                     // V d-rows w*16 + {0,8} + lr, cols j0..
        short* dK = bb + w * 1024 + lane * 8;
        short* dV = bb + 4096 + w * 1024 + lane * 8;
        ld16(kj, dK);               ld16(kj + 8 * DHEAD, dK + 512);
        ld16(vj, dV);               ld16(vj + 8 * SEQ,   dV + 512);
    };

    // ---- prologue: stage Q (128x64 = 16 KB, swizzled) through buf0, read frags
    {
        const short* qsrc = qbh + (size_t)(i0 + w * 32 + lr) * DHEAD + lc * 8;
        short* qdst = lds + w * 2048 + lane * 8;
#pragma unroll
        for (int qi = 0; qi < 4; qi++)
            ld16(qsrc + qi * 8 * DHEAD, qdst + qi * 512);
    }
    __syncthreads();                      // Q resident
    int coff[4];                          // swizzled col-granule offsets (shorts)
#pragma unroll
    for (int c = 0; c < 4; c++) coff[c] = ((c * 2 + h) ^ il7) * 8;
    bf16x8 aq[4];                         // Q B-operand frags: d = dc*16 + h*8 + e
#pragma unroll
    for (int dc = 0; dc < 4; dc++)
        aq[dc] = *(const bf16x8*)&lds[(w * 32 + il) * 64 + coff[dc]];
    __syncthreads();                      // all waves' Q reads done
    issueKV(0, lds);                      // tile 0 -> buf0 (overwrites Q)
    issueKV(64, lds + 8192);              // tile 1 -> buf1
    __syncthreads();                      // tiles 0,1 resident

    f32x16 oacc[2] = {};                  // O^T: d = dt*32 + (r&3)+8*(r>>2)+4h, i = il
    float sacc = 0.0f;                    // per-lane partial row sum (h-half of each j-tile)

    auto compute = [&](const short* bb) {
        const short* sKb = bb;
        const short* sVb = bb + 4096;
        // S^T = K @ Q^T : two 32x32 outputs (j-halves), 4 chained MFMAs each, 2 indep chains
        f32x16 s0 = {}, s1 = {};
        __builtin_amdgcn_s_setprio(1);
#pragma unroll
        for (int dc = 0; dc < 4; dc++) {
            bf16x8 k0 = *(const bf16x8*)&sKb[il * 64 + coff[dc]];
            bf16x8 k1 = *(const bf16x8*)&sKb[2048 + il * 64 + coff[dc]];
            s0 = MFMA32(k0, aq[dc], s0);
            s1 = MFMA32(k1, aq[dc], s1);
        }
        __builtin_amdgcn_s_setprio(0);

        // exp + pack for s0 (P element (h,e) <-> j = ks*16+4h+8*(e>>2)+(e&3) = s-reg order)
        float p0[16], p1[16];
#pragma unroll
        for (int r = 0; r < 16; r++) p0[r] = __builtin_amdgcn_exp2f(s0[r]);
        bf16x8 P0 = mk8(cvtpk(p0[0], p0[1]),  cvtpk(p0[2], p0[3]),
                        cvtpk(p0[4], p0[5]),  cvtpk(p0[6], p0[7]));
        bf16x8 P1 = mk8(cvtpk(p0[8], p0[9]),  cvtpk(p0[10], p0[11]),
                        cvtpk(p0[12], p0[13]), cvtpk(p0[14], p0[15]));

        // PV ks=0,1 while s1's softmax runs on VALU
        __builtin_amdgcn_s_setprio(1);
#pragma unroll
        for (int dt = 0; dt < 2; dt++) {
            bf16x8 vf0 = *(const bf16x8*)&sVb[dt * 2048 + il * 64 + coff[0]];
            oacc[dt] = MFMA32(vf0, P0, oacc[dt]);
            bf16x8 vf1 = *(const bf16x8*)&sVb[dt * 2048 + il * 64 + coff[1]];
            oacc[dt] = MFMA32(vf1, P1, oacc[dt]);
        }
        __builtin_amdgcn_s_setprio(0);

        // exp + pack for s1
#pragma unroll
        for (int r = 0; r < 16; r++) p1[r] = __builtin_amdgcn_exp2f(s1[r]);
        bf16x8 P2 = mk8(cvtpk(p1[0], p1[1]),  cvtpk(p1[2], p1[3]),
                        cvtpk(p1[4], p1[5]),  cvtpk(p1[6], p1[7]));
        bf16x8 P3 = mk8(cvtpk(p1[8], p1[9]),  cvtpk(p1[10], p1[11]),
                        cvtpk(p1[12], p1[13]), cvtpk(p1[14], p1[15]));

        // row-sum adds (independent of P) off the critical path
        float t0 = 0.f, t1 = 0.f, t2 = 0.f, t3 = 0.f;
#pragma unroll
        for (int r = 0; r < 16; r += 4) {
            t0 += p0[r]; t1 += p0[r + 1]; t2 += p0[r + 2]; t3 += p0[r + 3];
        }

        // PV ks=2,3
        __builtin_amdgcn_s_setprio(1);
#pragma unroll
        for (int dt = 0; dt < 2; dt++) {
            bf16x8 vf2 = *(const bf16x8*)&sVb[dt * 2048 + il * 64 + coff[2]];
            oacc[dt] = MFMA32(vf2, P2, oacc[dt]);
            bf16x8 vf3 = *(const bf16x8*)&sVb[dt * 2048 + il * 64 + coff[3]];
            oacc[dt] = MFMA32(vf3, P3, oacc[dt]);
        }
        __builtin_amdgcn_s_setprio(0);

#pragma unroll
        for (int r = 0; r < 16; r += 4) {
            t0 += p1[r]; t1 += p1[r + 1]; t2 += p1[r + 2]; t3 += p1[r + 3];
        }
        sacc += (t0 + t1) + (t2 + t3);
    };

    compute(lds);                         // tile 0
    for (int ti = 1; ti < 32; ti++) {
        __syncthreads();                  // tile ti resident; buf[(ti+1)&1] reads done
        if (ti < 31) issueKV((ti + 1) * 64, lds + ((ti + 1) & 1) * 8192);
        compute(lds + (ti & 1) * 8192);
    }

    // epilogue: full row sum = own half + lane^32 partner half
    float tot = sacc + __shfl_xor(sacc, 32, 64);
    float rl = 1.0f / tot;
    int b = bh >> 3, hh = bh & 7;
    int i = i0 + w * 32 + il;
    size_t base = ((size_t)(b * SEQ + i) * DIMK) + hh * DHEAD + h * 4;
#pragma unroll
    for (int dt = 0; dt < 2; dt++)
#pragma unroll
        for (int rq = 0; rq < 4; rq++) {  // d = dt*32 + rq*8 + 4h + {0..3}
            uint2 pv;
            pv.x = cvtpk(oacc[dt][4 * rq + 0] * rl, oacc[dt][4 * rq + 1] * rl);
            pv.y = cvtpk(oacc[dt][4 * rq + 2] * rl, oacc[dt][4 * rq + 3] * rl);
            *(uint2*)&o[base + dt * 32 + rq * 8] = pv;
        }
}

// ---------------------------------------------------------------- launch
extern "C" void kernel_launch(void* const* d_in, const int* in_sizes, int n_in,
                              void* d_out, int out_size, void* d_ws, size_t ws_size,
                              hipStream_t stream) {
    const float* x  = (const float*)d_in[0];
    const float* m  = (const float*)d_in[1];
    const float* Wq = (const float*)d_in[2];
    const float* Wk = (const float*)d_in[3];
    const float* Wv = (const float*)d_in[4];
    const float* Wo = (const float*)d_in[5];
    const float* bo = (const float*)d_in[6];
    float* out = (float*)d_out;

    char* ws = (char*)d_ws;
    const size_t XB_BYTES = (size_t)MROWS * DIMK * 2;      // 16 MiB
    const size_t WT_ONE   = (size_t)DIMK * DIMK;           // elements per weight
    short* xb  = (short*)(ws);
    short* mb  = (short*)(ws + XB_BYTES);
    short* wT  = (short*)(ws + 2 * XB_BYTES);              // 4 x 512x512 bf16 = 2 MiB
    short* qkv = (short*)(ws + 2 * XB_BYTES + 4 * WT_ONE * 2);
    short* ob  = xb;   // xb dead after projections; reuse as attention output

    cvt_kernel<<<16384, 256, 0, stream>>>(x, m, xb, mb);
    wtrans_kernel<<<dim3(16, 16, 4), dim3(32, 8), 0, stream>>>(Wq, Wk, Wv, Wo, wT);
    proj_q<<<dim3(4, 128), 256, 0, stream>>>(xb, wT, qkv);
    proj_kv<<<dim3(4, 128), 256, 0, stream>>>(mb, wT, qkv);
    attn_kernel<<<dim3(BATCH * HEADS, SEQ / 128), 256, 0, stream>>>(
        qkv, qkv + (size_t)MROWS * DIMK, qkv + 2 * (size_t)MROWS * DIMK, ob);
    out_proj<<<dim3(4, 128), 256, 0, stream>>>(ob, wT + 3 * WT_ONE, bo, out);
}

// Round 5
// 275.293 us; speedup vs baseline: 1.0776x; 1.0776x over previous
//
#include <hip/hip_runtime.h>
#include <hip/hip_bf16.h>

// Problem constants
#define DIMK   512
#define HEADS  8
#define DHEAD  64
#define SEQ    2048
#define BATCH  8
#define MROWS  (BATCH*SEQ)      // 16384
#define SCALE_LOG2E (0.044194173824159216f * 1.44269504088896340736f) // 512^-0.5 * log2(e)

typedef float fx4    __attribute__((ext_vector_type(4)));
typedef float f32x16 __attribute__((ext_vector_type(16)));
typedef short bf16x8 __attribute__((ext_vector_type(8)));
typedef short bf16x4 __attribute__((ext_vector_type(4)));

__device__ __forceinline__ short f2bf(float f) {
    union { float f; unsigned u; } x; x.f = f;
    unsigned r = (x.u + 0x7FFFu + ((x.u >> 16) & 1u)) >> 16;   // RNE
    return (short)r;
}

// pack two floats to two bf16 (round-half-up) in one dword via v_perm_b32
__device__ __forceinline__ unsigned pk2bf(float a, float b) {
    union { float f; unsigned u; } A, B; A.f = a; B.f = b;
    return __builtin_amdgcn_perm(B.u + 0x8000u, A.u + 0x8000u, 0x07060302u);
}

// single-instruction pack: dword = {bf16(a) lo, bf16(b) hi}, RNE
__device__ __forceinline__ unsigned cvtpk(float a, float b) {
    unsigned r;
    asm("v_cvt_pk_bf16_f32 %0, %1, %2" : "=v"(r) : "v"(a), "v"(b));
    return r;
}

__device__ __forceinline__ bf16x8 mk8(unsigned a, unsigned b, unsigned c, unsigned d) {
    union { unsigned u[4]; bf16x8 v; } x;
    x.u[0] = a; x.u[1] = b; x.u[2] = c; x.u[3] = d; return x.v;
}

// async global->LDS, 16B per lane; LDS dest = wave-uniform base + lane*16
__device__ __forceinline__ void ld16(const short* g, short* l) {
    __builtin_amdgcn_global_load_lds(
        (const __attribute__((address_space(1))) unsigned int*)g,
        (__attribute__((address_space(3))) unsigned int*)l, 16, 0, 0);
}

#define MFMA(a, b, c)   __builtin_amdgcn_mfma_f32_16x16x32_bf16(a, b, c, 0, 0, 0)
#define MFMA32(a, b, c) __builtin_amdgcn_mfma_f32_32x32x16_bf16(a, b, c, 0, 0, 0)

// ---------------------------------------------------------------- convert (x and m fused)
__global__ __launch_bounds__(256) void cvt_kernel(const float* __restrict__ x,
                                                  const float* __restrict__ m,
                                                  short* __restrict__ xb,
                                                  short* __restrict__ mb) {
    int bid = blockIdx.x;
    const float* src = (bid < 8192) ? x : m;
    short* dst = (bid < 8192) ? xb : mb;
    int i = (bid & 8191) * 256 + threadIdx.x;
    float4 v = ((const float4*)src)[i];
    bf16x4 o; o.x = f2bf(v.x); o.y = f2bf(v.y); o.z = f2bf(v.z); o.w = f2bf(v.w);
    ((bf16x4*)dst)[i] = o;
}

// ------------------------------------------------- weight transpose W[k][n] -> WT[n][k] bf16
__global__ __launch_bounds__(256) void wtrans_kernel(const float* __restrict__ Wq,
                                                     const float* __restrict__ Wk,
                                                     const float* __restrict__ Wv,
                                                     const float* __restrict__ Wo,
                                                     short* __restrict__ wT) {
    __shared__ float tile[32][33];
    const float* W = (blockIdx.z == 0) ? Wq : (blockIdx.z == 1) ? Wk
                   : (blockIdx.z == 2) ? Wv : Wo;
    short* dst = wT + (size_t)blockIdx.z * DIMK * DIMK;
    int n0 = blockIdx.x * 32, k0 = blockIdx.y * 32;
    int tx = threadIdx.x, ty = threadIdx.y;          // (32,8)
#pragma unroll
    for (int i = 0; i < 32; i += 8)
        tile[ty + i][tx] = W[(size_t)(k0 + ty + i) * DIMK + n0 + tx];
    __syncthreads();
#pragma unroll
    for (int i = 0; i < 32; i += 8)
        dst[(size_t)(n0 + ty + i) * DIMK + k0 + tx] = f2bf(tile[tx][ty + i]);
}

// ---------------------------------------------------------------- GEMM mainloop (m97-style)
// Stages A(128x512 act rows) and B(128x512 weight rows), BK=32, 16KB LDS, 2-barrier loop.
// OWN_B=0: acc[mt][nt] = D[act][weight] (lane: 4 consecutive act rows)
// OWN_B=1: acc[mi][nj] = D[weight][act] (lane: 4 consecutive weight rows = inner cols)
template<int OWN_B>
__device__ __forceinline__ void gemm97(const short* __restrict__ A,
                                       const short* __restrict__ B,
                                       short* lds, fx4 acc[2][8],
                                       int w, int lane, int q, int l15) {
    short* sA = lds;
    short* sB = lds + 4096;
    for (int k0 = 0; k0 < DIMK; k0 += 32) {
        __syncthreads();                         // prior iter's fragment reads complete
#pragma unroll
        for (int j = 0; j < 2; j++) {
            int c = w * 2 + j;
            ld16(A + (size_t)(c * 16 + l15) * DIMK + k0 + q * 8, sA + c * 512 + lane * 8);
            ld16(B + (size_t)(c * 16 + l15) * DIMK + k0 + q * 8, sB + c * 512 + lane * 8);
        }
        __syncthreads();                         // tile resident
        short* sOwn = OWN_B ? sB : sA;
        short* sAll = OWN_B ? sA : sB;
        bf16x8 o0 = *(bf16x8*)&sOwn[(w * 2 + 0) * 512 + lane * 8];
        bf16x8 o1 = *(bf16x8*)&sOwn[(w * 2 + 1) * 512 + lane * 8];
#pragma unroll
        for (int nt = 0; nt < 8; nt++) {
            bf16x8 f = *(bf16x8*)&sAll[nt * 512 + lane * 8];
            acc[0][nt] = MFMA(o0, f, acc[0][nt]);
            acc[1][nt] = MFMA(o1, f, acc[1][nt]);
        }
    }
}

// ---------------------------------------------------------------- fused QKV projection
// grid (4, 128, 3): x = inner tile, y = n tile, z = mode (0=q prescaled, 1=k, 2=v)
// (round-3 measured-good configuration, reverted from the round-4 split)
__global__ __launch_bounds__(256) void proj_qkv(const short* __restrict__ xb,
                                                const short* __restrict__ mb,
                                                const short* __restrict__ wT,
                                                short* __restrict__ qkv) {
    __shared__ __attribute__((aligned(16))) short lds[8192];
    int t = threadIdx.x, lane = t & 63, q = lane >> 4, l15 = lane & 15;
    int w = __builtin_amdgcn_readfirstlane(t >> 6);
    int mode = blockIdx.z;
    const short* A = ((mode == 0) ? xb : mb) + (size_t)blockIdx.y * 128 * DIMK;
    const short* B = wT + (size_t)mode * DIMK * DIMK + (size_t)blockIdx.x * 128 * DIMK;
    fx4 acc[2][8] = {};
    short* dst = qkv + (size_t)mode * MROWS * DIMK;

    if (mode < 2) {
        // D[inner][n]: lane holds 4 consecutive inner (d) -> b64 stores into [bh][n][d]
        gemm97<1>(A, B, lds, acc, w, lane, q, l15);
        float sc = (mode == 0) ? (float)SCALE_LOG2E : 1.0f;   // fold softmax scale into q
#pragma unroll
        for (int mi = 0; mi < 2; mi++) {
            int inner0 = blockIdx.x * 128 + w * 32 + mi * 16 + q * 4;
            int h = inner0 >> 6, d0 = inner0 & 63;
#pragma unroll
            for (int nj = 0; nj < 8; nj++) {
                int gn = blockIdx.y * 128 + nj * 16 + l15;
                int b = gn >> 11, n = gn & 2047;
                uint2 pv;
                pv.x = pk2bf(acc[mi][nj][0] * sc, acc[mi][nj][1] * sc);
                pv.y = pk2bf(acc[mi][nj][2] * sc, acc[mi][nj][3] * sc);
                *(uint2*)&dst[(((size_t)(b * 8 + h) * SEQ + n) << 6) + d0] = pv;
            }
        }
    } else {
        // D[n][inner]: lane holds 4 consecutive n (j) -> b64 stores into vT[bh*64+d][jperm]
        gemm97<0>(A, B, lds, acc, w, lane, q, l15);
#pragma unroll
        for (int mt = 0; mt < 2; mt++) {
            int gm0 = blockIdx.y * 128 + w * 32 + mt * 16 + q * 4;  // global act row base
            int b = gm0 >> 11, j0 = gm0 & 2047;
            // stored offset = true j with bits 2<->3 swapped (quad-aligned, self-inverse) so
            // attn's exchange-free P fragments pair with matching V elements.
            int jp = (j0 & ~12) | ((j0 & 8) >> 1) | ((j0 & 4) << 1);
#pragma unroll
            for (int nt = 0; nt < 8; nt++) {
                int inner = blockIdx.x * 128 + nt * 16 + l15;       // h*64+d
                uint2 pv;
                pv.x = pk2bf(acc[mt][nt][0], acc[mt][nt][1]);
                pv.y = pk2bf(acc[mt][nt][2], acc[mt][nt][3]);
                *(uint2*)&dst[((size_t)b * 512 + inner) * SEQ + jp] = pv;
            }
        }
    }
}

// ---------------------------------------------------------------- output projection (transposed)
// grid (4, 128): x = out-col tile, y = m tile. Lane holds 4 consecutive out-cols -> float4 stores.
__global__ __launch_bounds__(256) void out_proj(const short* __restrict__ ob,
                                                const short* __restrict__ woT,
                                                const float* __restrict__ bo,
                                                float* __restrict__ out) {
    __shared__ __attribute__((aligned(16))) short lds[8192];
    int t = threadIdx.x, lane = t & 63, q = lane >> 4, l15 = lane & 15;
    int w = __builtin_amdgcn_readfirstlane(t >> 6);
    const short* A = ob + (size_t)blockIdx.y * 128 * DIMK;
    const short* B = woT + (size_t)blockIdx.x * 128 * DIMK;
    fx4 acc[2][8] = {};
    gemm97<1>(A, B, lds, acc, w, lane, q, l15);

#pragma unroll
    for (int mi = 0; mi < 2; mi++) {
        int gn0 = blockIdx.x * 128 + w * 32 + mi * 16 + q * 4;  // out col base
        float4 b4 = *(const float4*)&bo[gn0];
#pragma unroll
        for (int nj = 0; nj < 8; nj++) {
            int n = blockIdx.y * 128 + nj * 16 + l15;           // act row
            float4 v;
            v.x = acc[mi][nj][0] + b4.x;
            v.y = acc[mi][nj][1] + b4.y;
            v.z = acc[mi][nj][2] + b4.z;
            v.w = acc[mi][nj][3] + b4.w;
            *(float4*)&out[(size_t)n * DIMK + gn0] = v;
        }
    }
}

// ---------------------------------------------------------------- flash attention
// (S^T form, 32x32 MFMA, cross-tile software pipeline)
// grid (64, 16). Wave w owns 32 q rows. KVBLK=64, THREE-buffer LDS rotation, one barrier/tile.
// Pipeline per tile t: [barrier] [stage(t+2) -> buf freed by tile t-1] [QK(t+1) MFMAs fill the
// matrix pipe] [SM(t) exp/pack on VALU, overlapping QK(t+1)] [PV(t) MFMAs]. Two live S-sets,
// statically indexed via unroll-by-2 role swap (rule #20). All LDS offsets/staging identical to
// the verified round-4 kernel; only scheduling and buffer count changed.
__global__ __launch_bounds__(256, 2) void attn_kernel(const short* __restrict__ qg,
                                                      const short* __restrict__ kg,
                                                      const short* __restrict__ vg,
                                                      short* __restrict__ o) {
    // 3 x [K 4096 | V 4096] shorts = 48 KB
    __shared__ __attribute__((aligned(16))) short lds[24576];
    int t = threadIdx.x, lane = t & 63;
    int il = lane & 31, h = lane >> 5, il7 = il & 7;
    int w = __builtin_amdgcn_readfirstlane(t >> 6);
    int bh = blockIdx.x;
    int i0 = blockIdx.y * 128;
    const short* qbh = qg + (size_t)bh * SEQ * DHEAD;

    // staging lane constants: row-sub = lane>>3 (8 rows/instr), swizzled col granule
    int lr = lane >> 3;
    int lc = (lane & 7) ^ lr;                        // source col granule for this lane
    const short* kbase = kg + (size_t)bh * SEQ * DHEAD + (size_t)(w * 16 + lr) * DHEAD + lc * 8;
    const short* vbase = vg + (size_t)bh * DHEAD * SEQ + (size_t)(w * 16 + lr) * SEQ + lc * 8;

    auto issueKV = [&](int j0, short* bb) {
        const short* kj = kbase + (size_t)j0 * DHEAD;     // K rows j0 + w*16 + {0,8} + lr
        const short* vj = vbase + j0;                     // V d-rows w*16 + {0,8} + lr, cols j0..
        short* dK = bb + w * 1024 + lane * 8;
        short* dV = bb + 4096 + w * 1024 + lane * 8;
        ld16(kj, dK);               ld16(kj + 8 * DHEAD, dK + 512);
        ld16(vj, dV);               ld16(vj + 8 * SEQ,   dV + 512);
    };

    // ---- prologue: stage Q (128x64 = 16 KB, swizzled) through buffer slot 0, read frags
    {
        const short* qsrc = qbh + (size_t)(i0 + w * 32 + lr) * DHEAD + lc * 8;
        short* qdst = lds + w * 2048 + lane * 8;
#pragma unroll
        for (int qi = 0; qi < 4; qi++)
            ld16(qsrc + qi * 8 * DHEAD, qdst + qi * 512);
    }
    __syncthreads();                      // Q resident
    int coff[4];                          // swizzled col-granule offsets (shorts)
#pragma unroll
    for (int c = 0; c < 4; c++) coff[c] = ((c * 2 + h) ^ il7) * 8;
    bf16x8 aq[4];                         // Q B-operand frags: d = dc*16 + h*8 + e
#pragma unroll
    for (int dc = 0; dc < 4; dc++)
        aq[dc] = *(const bf16x8*)&lds[(w * 32 + il) * 64 + coff[dc]];
    __syncthreads();                      // all waves' Q reads done

    short* b0 = lds;                      // buf(cur)
    short* b1 = lds + 8192;               // buf(cur+1)
    short* b2 = lds + 16384;              // buf(cur+2): staging target
    issueKV(0, b0);                       // tile 0 (overwrites Q)
    issueKV(64, b1);                      // tile 1
    __syncthreads();                      // tiles 0,1 resident

    f32x16 oacc[2] = {};                  // O^T: d = dt*32 + (r&3)+8*(r>>2)+4h, i = il
    float sacc = 0.0f;                    // per-lane partial row sum (h-half of each j-tile)

    // QK for one tile: S^T = K @ Q^T, two 32x32 j-halves, 4 chained MFMAs each
    auto stepQK = [&](const short* bK, f32x16& r0, f32x16& r1) {
        f32x16 z0 = {}, z1 = {};
        __builtin_amdgcn_s_setprio(1);
#pragma unroll
        for (int dc = 0; dc < 4; dc++) {
            bf16x8 k0 = *(const bf16x8*)&bK[il * 64 + coff[dc]];
            bf16x8 k1 = *(const bf16x8*)&bK[2048 + il * 64 + coff[dc]];
            z0 = MFMA32(k0, aq[dc], z0);
            z1 = MFMA32(k1, aq[dc], z1);
        }
        __builtin_amdgcn_s_setprio(0);
        r0 = z0; r1 = z1;
    };

    // SM + PV for one tile (consumes S computed one phase earlier; exchange-free P build)
    auto stepSMPV = [&](const short* bb, const f32x16& s0, const f32x16& s1) {
        const short* sVb = bb + 4096;
        float p0[16], p1[16];
#pragma unroll
        for (int r = 0; r < 16; r++) p0[r] = __builtin_amdgcn_exp2f(s0[r]);
#pragma unroll
        for (int r = 0; r < 16; r++) p1[r] = __builtin_amdgcn_exp2f(s1[r]);
        bf16x8 P0 = mk8(cvtpk(p0[0], p0[1]),   cvtpk(p0[2], p0[3]),
                        cvtpk(p0[4], p0[5]),   cvtpk(p0[6], p0[7]));
        bf16x8 P1 = mk8(cvtpk(p0[8], p0[9]),   cvtpk(p0[10], p0[11]),
                        cvtpk(p0[12], p0[13]), cvtpk(p0[14], p0[15]));
        bf16x8 P2 = mk8(cvtpk(p1[0], p1[1]),   cvtpk(p1[2], p1[3]),
                        cvtpk(p1[4], p1[5]),   cvtpk(p1[6], p1[7]));
        bf16x8 P3 = mk8(cvtpk(p1[8], p1[9]),   cvtpk(p1[10], p1[11]),
                        cvtpk(p1[12], p1[13]), cvtpk(p1[14], p1[15]));
        __builtin_amdgcn_s_setprio(1);
#pragma unroll
        for (int dt = 0; dt < 2; dt++) {
            bf16x8 vf0 = *(const bf16x8*)&sVb[dt * 2048 + il * 64 + coff[0]];
            oacc[dt] = MFMA32(vf0, P0, oacc[dt]);
            bf16x8 vf1 = *(const bf16x8*)&sVb[dt * 2048 + il * 64 + coff[1]];
            oacc[dt] = MFMA32(vf1, P1, oacc[dt]);
            bf16x8 vf2 = *(const bf16x8*)&sVb[dt * 2048 + il * 64 + coff[2]];
            oacc[dt] = MFMA32(vf2, P2, oacc[dt]);
            bf16x8 vf3 = *(const bf16x8*)&sVb[dt * 2048 + il * 64 + coff[3]];
            oacc[dt] = MFMA32(vf3, P3, oacc[dt]);
        }
        __builtin_amdgcn_s_setprio(0);
        float t0 = 0.f, t1 = 0.f, t2 = 0.f, t3 = 0.f;
#pragma unroll
        for (int r = 0; r < 16; r += 4) {
            t0 += p0[r]; t1 += p0[r + 1]; t2 += p0[r + 2]; t3 += p0[r + 3];
            t0 += p1[r]; t1 += p1[r + 1]; t2 += p1[r + 2]; t3 += p1[r + 3];
        }
        sacc += (t0 + t1) + (t2 + t3);
    };

    f32x16 sA0, sA1, sB0, sB1;            // two live S-sets (role-swapped, static indexing)
    stepQK(b0, sA0, sA1);                 // S(0)

    for (int ti = 0; ti < 30; ti += 2) {
        // ---- even tile ti: cur S = sA
        __syncthreads();                  // stage(ti+1) resident; reads of b2's old tile done
        issueKV((ti + 2) * 64, b2);
        stepQK(b1, sB0, sB1);             // S(ti+1) fills matrix pipe
        stepSMPV(b0, sA0, sA1);           // SM(ti) on VALU overlaps, then PV(ti)
        short* tp = b0; b0 = b1; b1 = b2; b2 = tp;
        // ---- odd tile ti+1: cur S = sB
        __syncthreads();
        issueKV((ti + 3) * 64, b2);
        stepQK(b1, sA0, sA1);             // S(ti+2)
        stepSMPV(b0, sB0, sB1);           // SM+PV(ti+1)
        tp = b0; b0 = b1; b1 = b2; b2 = tp;
    }
    // ---- tail: tiles 30, 31 (no further staging)
    __syncthreads();                      // stage(31) resident
    stepQK(b1, sB0, sB1);                 // S(31)
    stepSMPV(b0, sA0, sA1);               // tile 30
    { short* tp = b0; b0 = b1; b1 = b2; b2 = tp; }
    stepSMPV(b0, sB0, sB1);               // tile 31

    // epilogue: full row sum = own half + lane^32 partner half
    float tot = sacc + __shfl_xor(sacc, 32, 64);
    float rl = 1.0f / tot;
    int b = bh >> 3, hh = bh & 7;
    int i = i0 + w * 32 + il;
    size_t base = ((size_t)(b * SEQ + i) * DIMK) + hh * DHEAD + h * 4;
#pragma unroll
    for (int dt = 0; dt < 2; dt++)
#pragma unroll
        for (int rq = 0; rq < 4; rq++) {  // d = dt*32 + rq*8 + 4h + {0..3}
            uint2 pv;
            pv.x = cvtpk(oacc[dt][4 * rq + 0] * rl, oacc[dt][4 * rq + 1] * rl);
            pv.y = cvtpk(oacc[dt][4 * rq + 2] * rl, oacc[dt][4 * rq + 3] * rl);
            *(uint2*)&o[base + dt * 32 + rq * 8] = pv;
        }
}

// ---------------------------------------------------------------- launch
extern "C" void kernel_launch(void* const* d_in, const int* in_sizes, int n_in,
                              void* d_out, int out_size, void* d_ws, size_t ws_size,
                              hipStream_t stream) {
    const float* x  = (const float*)d_in[0];
    const float* m  = (const float*)d_in[1];
    const float* Wq = (const float*)d_in[2];
    const float* Wk = (const float*)d_in[3];
    const float* Wv = (const float*)d_in[4];
    const float* Wo = (const float*)d_in[5];
    const float* bo = (const float*)d_in[6];
    float* out = (float*)d_out;

    char* ws = (char*)d_ws;
    const size_t XB_BYTES = (size_t)MROWS * DIMK * 2;      // 16 MiB
    const size_t WT_ONE   = (size_t)DIMK * DIMK;           // elements per weight
    short* xb  = (short*)(ws);
    short* mb  = (short*)(ws + XB_BYTES);
    short* wT  = (short*)(ws + 2 * XB_BYTES);              // 4 x 512x512 bf16 = 2 MiB
    short* qkv = (short*)(ws + 2 * XB_BYTES + 4 * WT_ONE * 2);
    short* ob  = xb;   // xb dead after proj_qkv; reuse as attention output

    cvt_kernel<<<16384, 256, 0, stream>>>(x, m, xb, mb);
    wtrans_kernel<<<dim3(16, 16, 4), dim3(32, 8), 0, stream>>>(Wq, Wk, Wv, Wo, wT);
    proj_qkv<<<dim3(4, 128, 3), 256, 0, stream>>>(xb, mb, wT, qkv);
    attn_kernel<<<dim3(BATCH * HEADS, SEQ / 128), 256, 0, stream>>>(
        qkv, qkv + (size_t)MROWS * DIMK, qkv + 2 * (size_t)MROWS * DIMK, ob);
    out_proj<<<dim3(4, 128), 256, 0, stream>>>(ob, wT + 3 * WT_ONE, bo, out);
}

// Round 6
// 272.577 us; speedup vs baseline: 1.0883x; 1.0100x over previous
//
#include <hip/hip_runtime.h>
#include <hip/hip_bf16.h>

// Problem constants
#define DIMK   512
#define HEADS  8
#define DHEAD  64
#define SEQ    2048
#define BATCH  8
#define MROWS  (BATCH*SEQ)      // 16384
#define SCALE_LOG2E (0.044194173824159216f * 1.44269504088896340736f) // 512^-0.5 * log2(e)

typedef float fx4    __attribute__((ext_vector_type(4)));
typedef float f32x16 __attribute__((ext_vector_type(16)));
typedef short bf16x8 __attribute__((ext_vector_type(8)));
typedef short bf16x4 __attribute__((ext_vector_type(4)));

__device__ __forceinline__ short f2bf(float f) {
    union { float f; unsigned u; } x; x.f = f;
    unsigned r = (x.u + 0x7FFFu + ((x.u >> 16) & 1u)) >> 16;   // RNE
    return (short)r;
}

// pack two floats to two bf16 (round-half-up) in one dword via v_perm_b32
__device__ __forceinline__ unsigned pk2bf(float a, float b) {
    union { float f; unsigned u; } A, B; A.f = a; B.f = b;
    return __builtin_amdgcn_perm(B.u + 0x8000u, A.u + 0x8000u, 0x07060302u);
}

// single-instruction pack: dword = {bf16(a) lo, bf16(b) hi}, RNE
__device__ __forceinline__ unsigned cvtpk(float a, float b) {
    unsigned r;
    asm("v_cvt_pk_bf16_f32 %0, %1, %2" : "=v"(r) : "v"(a), "v"(b));
    return r;
}

__device__ __forceinline__ bf16x8 mk8(unsigned a, unsigned b, unsigned c, unsigned d) {
    union { unsigned u[4]; bf16x8 v; } x;
    x.u[0] = a; x.u[1] = b; x.u[2] = c; x.u[3] = d; return x.v;
}

// async global->LDS, 16B per lane; LDS dest = wave-uniform base + lane*16
__device__ __forceinline__ void ld16(const short* g, short* l) {
    __builtin_amdgcn_global_load_lds(
        (const __attribute__((address_space(1))) unsigned int*)g,
        (__attribute__((address_space(3))) unsigned int*)l, 16, 0, 0);
}

#define MFMA(a, b, c)   __builtin_amdgcn_mfma_f32_16x16x32_bf16(a, b, c, 0, 0, 0)
#define MFMA32(a, b, c) __builtin_amdgcn_mfma_f32_32x32x16_bf16(a, b, c, 0, 0, 0)

// ---------------------------------------------------------------- convert (x and m fused)
__global__ __launch_bounds__(256) void cvt_kernel(const float* __restrict__ x,
                                                  const float* __restrict__ m,
                                                  short* __restrict__ xb,
                                                  short* __restrict__ mb) {
    int bid = blockIdx.x;
    const float* src = (bid < 8192) ? x : m;
    short* dst = (bid < 8192) ? xb : mb;
    int i = (bid & 8191) * 256 + threadIdx.x;
    float4 v = ((const float4*)src)[i];
    bf16x4 o; o.x = f2bf(v.x); o.y = f2bf(v.y); o.z = f2bf(v.z); o.w = f2bf(v.w);
    ((bf16x4*)dst)[i] = o;
}

// ------------------------------------------------- weight transpose W[k][n] -> WT[n][k] bf16
__global__ __launch_bounds__(256) void wtrans_kernel(const float* __restrict__ Wq,
                                                     const float* __restrict__ Wk,
                                                     const float* __restrict__ Wv,
                                                     const float* __restrict__ Wo,
                                                     short* __restrict__ wT) {
    __shared__ float tile[32][33];
    const float* W = (blockIdx.z == 0) ? Wq : (blockIdx.z == 1) ? Wk
                   : (blockIdx.z == 2) ? Wv : Wo;
    short* dst = wT + (size_t)blockIdx.z * DIMK * DIMK;
    int n0 = blockIdx.x * 32, k0 = blockIdx.y * 32;
    int tx = threadIdx.x, ty = threadIdx.y;          // (32,8)
#pragma unroll
    for (int i = 0; i < 32; i += 8)
        tile[ty + i][tx] = W[(size_t)(k0 + ty + i) * DIMK + n0 + tx];
    __syncthreads();
#pragma unroll
    for (int i = 0; i < 32; i += 8)
        dst[(size_t)(n0 + ty + i) * DIMK + k0 + tx] = f2bf(tile[tx][ty + i]);
}

// ---------------------------------------------------------------- GEMM mainloop (m97-style)
// Stages A(128x512 act rows) and B(128x512 weight rows), BK=32, 16KB LDS, 2-barrier loop.
// OWN_B=0: acc[mt][nt] = D[act][weight] (lane: 4 consecutive act rows)
// OWN_B=1: acc[mi][nj] = D[weight][act] (lane: 4 consecutive weight rows = inner cols)
template<int OWN_B>
__device__ __forceinline__ void gemm97(const short* __restrict__ A,
                                       const short* __restrict__ B,
                                       short* lds, fx4 acc[2][8],
                                       int w, int lane, int q, int l15) {
    short* sA = lds;
    short* sB = lds + 4096;
    for (int k0 = 0; k0 < DIMK; k0 += 32) {
        __syncthreads();                         // prior iter's fragment reads complete
#pragma unroll
        for (int j = 0; j < 2; j++) {
            int c = w * 2 + j;
            ld16(A + (size_t)(c * 16 + l15) * DIMK + k0 + q * 8, sA + c * 512 + lane * 8);
            ld16(B + (size_t)(c * 16 + l15) * DIMK + k0 + q * 8, sB + c * 512 + lane * 8);
        }
        __syncthreads();                         // tile resident
        short* sOwn = OWN_B ? sB : sA;
        short* sAll = OWN_B ? sA : sB;
        bf16x8 o0 = *(bf16x8*)&sOwn[(w * 2 + 0) * 512 + lane * 8];
        bf16x8 o1 = *(bf16x8*)&sOwn[(w * 2 + 1) * 512 + lane * 8];
#pragma unroll
        for (int nt = 0; nt < 8; nt++) {
            bf16x8 f = *(bf16x8*)&sAll[nt * 512 + lane * 8];
            acc[0][nt] = MFMA(o0, f, acc[0][nt]);
            acc[1][nt] = MFMA(o1, f, acc[1][nt]);
        }
    }
}

// ---------------------------------------------------------------- fused QKV projection
// grid (4, 128, 3): x = inner tile, y = n tile, z = mode (0=q prescaled, 1=k, 2=v)
// (round-3 measured-good configuration)
__global__ __launch_bounds__(256) void proj_qkv(const short* __restrict__ xb,
                                                const short* __restrict__ mb,
                                                const short* __restrict__ wT,
                                                short* __restrict__ qkv) {
    __shared__ __attribute__((aligned(16))) short lds[8192];
    int t = threadIdx.x, lane = t & 63, q = lane >> 4, l15 = lane & 15;
    int w = __builtin_amdgcn_readfirstlane(t >> 6);
    int mode = blockIdx.z;
    const short* A = ((mode == 0) ? xb : mb) + (size_t)blockIdx.y * 128 * DIMK;
    const short* B = wT + (size_t)mode * DIMK * DIMK + (size_t)blockIdx.x * 128 * DIMK;
    fx4 acc[2][8] = {};
    short* dst = qkv + (size_t)mode * MROWS * DIMK;

    if (mode < 2) {
        // D[inner][n]: lane holds 4 consecutive inner (d) -> b64 stores into [bh][n][d]
        gemm97<1>(A, B, lds, acc, w, lane, q, l15);
        float sc = (mode == 0) ? (float)SCALE_LOG2E : 1.0f;   // fold softmax scale into q
#pragma unroll
        for (int mi = 0; mi < 2; mi++) {
            int inner0 = blockIdx.x * 128 + w * 32 + mi * 16 + q * 4;
            int h = inner0 >> 6, d0 = inner0 & 63;
#pragma unroll
            for (int nj = 0; nj < 8; nj++) {
                int gn = blockIdx.y * 128 + nj * 16 + l15;
                int b = gn >> 11, n = gn & 2047;
                uint2 pv;
                pv.x = pk2bf(acc[mi][nj][0] * sc, acc[mi][nj][1] * sc);
                pv.y = pk2bf(acc[mi][nj][2] * sc, acc[mi][nj][3] * sc);
                *(uint2*)&dst[(((size_t)(b * 8 + h) * SEQ + n) << 6) + d0] = pv;
            }
        }
    } else {
        // D[n][inner]: lane holds 4 consecutive n (j) -> b64 stores into vT[bh*64+d][jperm]
        gemm97<0>(A, B, lds, acc, w, lane, q, l15);
#pragma unroll
        for (int mt = 0; mt < 2; mt++) {
            int gm0 = blockIdx.y * 128 + w * 32 + mt * 16 + q * 4;  // global act row base
            int b = gm0 >> 11, j0 = gm0 & 2047;
            // stored offset = true j with bits 2<->3 swapped (quad-aligned, self-inverse) so
            // attn's exchange-free P fragments pair with matching V elements.
            int jp = (j0 & ~12) | ((j0 & 8) >> 1) | ((j0 & 4) << 1);
#pragma unroll
            for (int nt = 0; nt < 8; nt++) {
                int inner = blockIdx.x * 128 + nt * 16 + l15;       // h*64+d
                uint2 pv;
                pv.x = pk2bf(acc[mt][nt][0], acc[mt][nt][1]);
                pv.y = pk2bf(acc[mt][nt][2], acc[mt][nt][3]);
                *(uint2*)&dst[((size_t)b * 512 + inner) * SEQ + jp] = pv;
            }
        }
    }
}

// ---------------------------------------------------------------- output projection (transposed)
// grid (4, 128): x = out-col tile, y = m tile. Lane holds 4 consecutive out-cols -> float4 stores.
__global__ __launch_bounds__(256) void out_proj(const short* __restrict__ ob,
                                                const short* __restrict__ woT,
                                                const float* __restrict__ bo,
                                                float* __restrict__ out) {
    __shared__ __attribute__((aligned(16))) short lds[8192];
    int t = threadIdx.x, lane = t & 63, q = lane >> 4, l15 = lane & 15;
    int w = __builtin_amdgcn_readfirstlane(t >> 6);
    const short* A = ob + (size_t)blockIdx.y * 128 * DIMK;
    const short* B = woT + (size_t)blockIdx.x * 128 * DIMK;
    fx4 acc[2][8] = {};
    gemm97<1>(A, B, lds, acc, w, lane, q, l15);

#pragma unroll
    for (int mi = 0; mi < 2; mi++) {
        int gn0 = blockIdx.x * 128 + w * 32 + mi * 16 + q * 4;  // out col base
        float4 b4 = *(const float4*)&bo[gn0];
#pragma unroll
        for (int nj = 0; nj < 8; nj++) {
            int n = blockIdx.y * 128 + nj * 16 + l15;           // act row
            float4 v;
            v.x = acc[mi][nj][0] + b4.x;
            v.y = acc[mi][nj][1] + b4.y;
            v.z = acc[mi][nj][2] + b4.z;
            v.w = acc[mi][nj][3] + b4.w;
            *(float4*)&out[(size_t)n * DIMK + gn0] = v;
        }
    }
}

// ---------------------------------------------------------------- flash attention (S^T form, 32x32 MFMA)
// grid (64, 16). Wave w owns 32 q rows. KVBLK=64, DOUBLE-buffered K/V in LDS (32 KB — the
// measured-best round-4 config; the 3-buffer pipeline regressed via occupancy + L2-reuse loss).
// 16B-granule XOR swizzle (pre-swizzled global source, linear LDS dest, matching swizzled read).
// Softmax fully in-register and exchange-free; V pre-permuted at store (proj_qkv).
// PV MFMAs for P[0..1] issue BETWEEN the two exp/pack VALU bursts; row-sum adds off-path.
__global__ __launch_bounds__(256, 4) void attn_kernel(const short* __restrict__ qg,
                                                      const short* __restrict__ kg,
                                                      const short* __restrict__ vg,
                                                      short* __restrict__ o) {
    // [buf0: K 4096 | V 4096][buf1: K | V] shorts = 32 KB
    __shared__ __attribute__((aligned(16))) short lds[16384];
    int t = threadIdx.x, lane = t & 63;
    int il = lane & 31, h = lane >> 5, il7 = il & 7;
    int w = __builtin_amdgcn_readfirstlane(t >> 6);
    int bh = blockIdx.x;
    int i0 = blockIdx.y * 128;
    const short* qbh = qg + (size_t)bh * SEQ * DHEAD;

    // staging lane constants: row-sub = lane>>3 (8 rows/instr), swizzled col granule
    int lr = lane >> 3;
    int lc = (lane & 7) ^ lr;                        // source col granule for this lane
    const short* kbase = kg + (size_t)bh * SEQ * DHEAD + (size_t)(w * 16 + lr) * DHEAD + lc * 8;
    const short* vbase = vg + (size_t)bh * DHEAD * SEQ + (size_t)(w * 16 + lr) * SEQ + lc * 8;

    auto issueKV = [&](int j0, short* bb) {
        const short* kj = kbase + (size_t)j0 * DHEAD;     // K rows j0 + w*16 + {0,8} + lr
        const short* vj = vbase + j0;                     // V d-rows w*16 + {0,8} + lr, cols j0..
        short* dK = bb + w * 1024 + lane * 8;
        short* dV = bb + 4096 + w * 1024 + lane * 8;
        ld16(kj, dK);               ld16(kj + 8 * DHEAD, dK + 512);
        ld16(vj, dV);               ld16(vj + 8 * SEQ,   dV + 512);
    };

    // ---- prologue: stage Q (128x64 = 16 KB, swizzled) through buf0, read frags
    {
        const short* qsrc = qbh + (size_t)(i0 + w * 32 + lr) * DHEAD + lc * 8;
        short* qdst = lds + w * 2048 + lane * 8;
#pragma unroll
        for (int qi = 0; qi < 4; qi++)
            ld16(qsrc + qi * 8 * DHEAD, qdst + qi * 512);
    }
    __syncthreads();                      // Q resident
    int coff[4];                          // swizzled col-granule offsets (shorts)
#pragma unroll
    for (int c = 0; c < 4; c++) coff[c] = ((c * 2 + h) ^ il7) * 8;
    bf16x8 aq[4];                         // Q B-operand frags: d = dc*16 + h*8 + e
#pragma unroll
    for (int dc = 0; dc < 4; dc++)
        aq[dc] = *(const bf16x8*)&lds[(w * 32 + il) * 64 + coff[dc]];
    __syncthreads();                      // all waves' Q reads done
    issueKV(0, lds);                      // tile 0 -> buf0 (overwrites Q)
    issueKV(64, lds + 8192);              // tile 1 -> buf1
    __syncthreads();                      // tiles 0,1 resident

    f32x16 oacc[2] = {};                  // O^T: d = dt*32 + (r&3)+8*(r>>2)+4h, i = il
    float sacc = 0.0f;                    // per-lane partial row sum (h-half of each j-tile)

    auto compute = [&](const short* bb) {
        const short* sKb = bb;
        const short* sVb = bb + 4096;
        // S^T = K @ Q^T : two 32x32 outputs (j-halves), 4 chained MFMAs each, 2 indep chains
        f32x16 s0 = {}, s1 = {};
        __builtin_amdgcn_s_setprio(1);
#pragma unroll
        for (int dc = 0; dc < 4; dc++) {
            bf16x8 k0 = *(const bf16x8*)&sKb[il * 64 + coff[dc]];
            bf16x8 k1 = *(const bf16x8*)&sKb[2048 + il * 64 + coff[dc]];
            s0 = MFMA32(k0, aq[dc], s0);
            s1 = MFMA32(k1, aq[dc], s1);
        }
        __builtin_amdgcn_s_setprio(0);

        // exp + pack for s0 (P element (h,e) <-> j = ks*16+4h+8*(e>>2)+(e&3) = s-reg order)
        float p0[16], p1[16];
#pragma unroll
        for (int r = 0; r < 16; r++) p0[r] = __builtin_amdgcn_exp2f(s0[r]);
        bf16x8 P0 = mk8(cvtpk(p0[0], p0[1]),  cvtpk(p0[2], p0[3]),
                        cvtpk(p0[4], p0[5]),  cvtpk(p0[6], p0[7]));
        bf16x8 P1 = mk8(cvtpk(p0[8], p0[9]),  cvtpk(p0[10], p0[11]),
                        cvtpk(p0[12], p0[13]), cvtpk(p0[14], p0[15]));

        // PV ks=0,1 while s1's softmax runs on VALU
        __builtin_amdgcn_s_setprio(1);
#pragma unroll
        for (int dt = 0; dt < 2; dt++) {
            bf16x8 vf0 = *(const bf16x8*)&sVb[dt * 2048 + il * 64 + coff[0]];
            oacc[dt] = MFMA32(vf0, P0, oacc[dt]);
            bf16x8 vf1 = *(const bf16x8*)&sVb[dt * 2048 + il * 64 + coff[1]];
            oacc[dt] = MFMA32(vf1, P1, oacc[dt]);
        }
        __builtin_amdgcn_s_setprio(0);

        // exp + pack for s1
#pragma unroll
        for (int r = 0; r < 16; r++) p1[r] = __builtin_amdgcn_exp2f(s1[r]);
        bf16x8 P2 = mk8(cvtpk(p1[0], p1[1]),  cvtpk(p1[2], p1[3]),
                        cvtpk(p1[4], p1[5]),  cvtpk(p1[6], p1[7]));
        bf16x8 P3 = mk8(cvtpk(p1[8], p1[9]),  cvtpk(p1[10], p1[11]),
                        cvtpk(p1[12], p1[13]), cvtpk(p1[14], p1[15]));

        // row-sum adds (independent of P) off the critical path
        float t0 = 0.f, t1 = 0.f, t2 = 0.f, t3 = 0.f;
#pragma unroll
        for (int r = 0; r < 16; r += 4) {
            t0 += p0[r]; t1 += p0[r + 1]; t2 += p0[r + 2]; t3 += p0[r + 3];
        }

        // PV ks=2,3
        __builtin_amdgcn_s_setprio(1);
#pragma unroll
        for (int dt = 0; dt < 2; dt++) {
            bf16x8 vf2 = *(const bf16x8*)&sVb[dt * 2048 + il * 64 + coff[2]];
            oacc[dt] = MFMA32(vf2, P2, oacc[dt]);
            bf16x8 vf3 = *(const bf16x8*)&sVb[dt * 2048 + il * 64 + coff[3]];
            oacc[dt] = MFMA32(vf3, P3, oacc[dt]);
        }
        __builtin_amdgcn_s_setprio(0);

#pragma unroll
        for (int r = 0; r < 16; r += 4) {
            t0 += p1[r]; t1 += p1[r + 1]; t2 += p1[r + 2]; t3 += p1[r + 3];
        }
        sacc += (t0 + t1) + (t2 + t3);
    };

    compute(lds);                         // tile 0
    for (int ti = 1; ti < 32; ti++) {
        __syncthreads();                  // tile ti resident; buf[(ti+1)&1] reads done
        if (ti < 31) issueKV((ti + 1) * 64, lds + ((ti + 1) & 1) * 8192);
        compute(lds + (ti & 1) * 8192);
    }

    // epilogue: full row sum = own half + lane^32 partner half
    float tot = sacc + __shfl_xor(sacc, 32, 64);
    float rl = 1.0f / tot;
    int b = bh >> 3, hh = bh & 7;
    int i = i0 + w * 32 + il;
    size_t base = ((size_t)(b * SEQ + i) * DIMK) + hh * DHEAD + h * 4;
#pragma unroll
    for (int dt = 0; dt < 2; dt++)
#pragma unroll
        for (int rq = 0; rq < 4; rq++) {  // d = dt*32 + rq*8 + 4h + {0..3}
            uint2 pv;
            pv.x = cvtpk(oacc[dt][4 * rq + 0] * rl, oacc[dt][4 * rq + 1] * rl);
            pv.y = cvtpk(oacc[dt][4 * rq + 2] * rl, oacc[dt][4 * rq + 3] * rl);
            *(uint2*)&o[base + dt * 32 + rq * 8] = pv;
        }
}

// ---------------------------------------------------------------- launch
extern "C" void kernel_launch(void* const* d_in, const int* in_sizes, int n_in,
                              void* d_out, int out_size, void* d_ws, size_t ws_size,
                              hipStream_t stream) {
    const float* x  = (const float*)d_in[0];
    const float* m  = (const float*)d_in[1];
    const float* Wq = (const float*)d_in[2];
    const float* Wk = (const float*)d_in[3];
    const float* Wv = (const float*)d_in[4];
    const float* Wo = (const float*)d_in[5];
    const float* bo = (const float*)d_in[6];
    float* out = (float*)d_out;

    char* ws = (char*)d_ws;
    const size_t XB_BYTES = (size_t)MROWS * DIMK * 2;      // 16 MiB
    const size_t WT_ONE   = (size_t)DIMK * DIMK;           // elements per weight
    short* xb  = (short*)(ws);
    short* mb  = (short*)(ws + XB_BYTES);
    short* wT  = (short*)(ws + 2 * XB_BYTES);              // 4 x 512x512 bf16 = 2 MiB
    short* qkv = (short*)(ws + 2 * XB_BYTES + 4 * WT_ONE * 2);
    short* ob  = xb;   // xb dead after proj_qkv; reuse as attention output

    cvt_kernel<<<16384, 256, 0, stream>>>(x, m, xb, mb);
    wtrans_kernel<<<dim3(16, 16, 4), dim3(32, 8), 0, stream>>>(Wq, Wk, Wv, Wo, wT);
    proj_qkv<<<dim3(4, 128, 3), 256, 0, stream>>>(xb, mb, wT, qkv);
    attn_kernel<<<dim3(BATCH * HEADS, SEQ / 128), 256, 0, stream>>>(
        qkv, qkv + (size_t)MROWS * DIMK, qkv + 2 * (size_t)MROWS * DIMK, ob);
    out_proj<<<dim3(4, 128), 256, 0, stream>>>(ob, wT + 3 * WT_ONE, bo, out);
}